// Round 13
// baseline (12929.961 us; speedup 1.0000x reference)
//
#include <hip/hip_runtime.h>
#include <stdint.h>

typedef short s16x8 __attribute__((ext_vector_type(8)));
typedef float f32x4 __attribute__((ext_vector_type(4)));
typedef uint  u32x4 __attribute__((ext_vector_type(4)));

#define DEV static __device__ __forceinline__

DEV float bf2f(ushort u){ union{uint i;float f;}v; v.i=((uint)u)<<16; return v.f; }
DEV ushort f2bf(float f){ union{float f;uint i;}v; v.f=f; return (ushort)((v.i + 0x7FFFu + ((v.i>>16)&1u))>>16); }
DEV float fsigmoid(float x){ return 1.f/(1.f+__expf(-x)); }
DEV float fgelu(float x){
  float u = 0.7978845608028654f*(x + 0.044715f*x*x*x);
  float e = __expf(2.f*u);
  float th = 1.f - 2.f/(e+1.f);
  return 0.5f*x*(1.f+th);
}
DEV f32x4 mfma16(s16x8 a, s16x8 b, f32x4 c){
  return __builtin_amdgcn_mfma_f32_16x16x32_bf16(a,b,c,0,0,0);
}

// system-scope (sc0 sc1) helpers — r6-proven coherent path
DEV void store_u64_coherent(unsigned long long* p, unsigned long long v){
  asm volatile("global_store_dwordx2 %0, %1, off sc0 sc1" :: "v"(p), "v"(v) : "memory");
}
DEV void store_f32_coherent(float* p, float v){
  asm volatile("global_store_dword %0, %1, off sc0 sc1" :: "v"(p), "v"(v) : "memory");
}
DEV void load8_u64_coherent(const unsigned long long* p, u32x4& r0, u32x4& r1,
                            u32x4& r2, u32x4& r3){
  asm volatile("global_load_dwordx4 %0, %4, off sc0 sc1\n\t"
               "global_load_dwordx4 %1, %4, off offset:16 sc0 sc1\n\t"
               "global_load_dwordx4 %2, %4, off offset:32 sc0 sc1\n\t"
               "global_load_dwordx4 %3, %4, off offset:48 sc0 sc1\n\t"
               "s_waitcnt vmcnt(0)"
               : "=&v"(r0), "=&v"(r1), "=&v"(r2), "=&v"(r3)
               : "v"(p) : "memory");
}
DEV unsigned long long load_u64_coherent(const unsigned long long* p){
  unsigned long long v;
  asm volatile("global_load_dwordx2 %0, %1, off sc0 sc1\n\ts_waitcnt vmcnt(0)"
               : "=v"(v) : "v"(p) : "memory");
  return v;
}
// batched coherent read of 32 consecutive floats (128B)
DEV void load8x16_coh(const float* p, f32x4 r[8]){
  asm volatile(
    "global_load_dwordx4 %0, %8, off sc0 sc1\n\t"
    "global_load_dwordx4 %1, %8, off offset:16 sc0 sc1\n\t"
    "global_load_dwordx4 %2, %8, off offset:32 sc0 sc1\n\t"
    "global_load_dwordx4 %3, %8, off offset:48 sc0 sc1\n\t"
    "global_load_dwordx4 %4, %8, off offset:64 sc0 sc1\n\t"
    "global_load_dwordx4 %5, %8, off offset:80 sc0 sc1\n\t"
    "global_load_dwordx4 %6, %8, off offset:96 sc0 sc1\n\t"
    "global_load_dwordx4 %7, %8, off offset:112 sc0 sc1\n\t"
    "s_waitcnt vmcnt(0)"
    : "=&v"(r[0]), "=&v"(r[1]), "=&v"(r[2]), "=&v"(r[3]),
      "=&v"(r[4]), "=&v"(r[5]), "=&v"(r[6]), "=&v"(r[7])
    : "v"(p) : "memory");
}

// ---------------- transpose + f32->bf16 convert: dst[N][K] = bf16(src[K][N]) ----------------
__global__ __launch_bounds__(256) void transpose_cvt(const float* __restrict__ src,
                                                     ushort* __restrict__ dst, int K, int N){
  __shared__ float tile[64][65];
  int tk = blockIdx.y*64, tn = blockIdx.x*64;
  int t = threadIdx.x;
  int c4 = (t & 15)*4, r0 = t >> 4;
  #pragma unroll
  for (int p=0;p<4;++p){
    int r = r0 + p*16;
    float4 v = *(const float4*)(src + (size_t)(tk+r)*N + tn + c4);
    tile[r][c4+0]=v.x; tile[r][c4+1]=v.y; tile[r][c4+2]=v.z; tile[r][c4+3]=v.w;
  }
  __syncthreads();
  #pragma unroll
  for (int p=0;p<4;++p){
    int n = r0 + p*16;
    ushort4 o = make_ushort4(f2bf(tile[c4+0][n]), f2bf(tile[c4+1][n]),
                             f2bf(tile[c4+2][n]), f2bf(tile[c4+3][n]));
    *(ushort4*)(dst + (size_t)(tn+n)*K + tk + c4) = o;
  }
}

// ---------------- elementwise f32->bf16 ----------------
__global__ __launch_bounds__(256) void cvt_bf16(const float* __restrict__ s,
                                                ushort* __restrict__ d, int n){
  int i = (blockIdx.x*256 + threadIdx.x)*4;
  if (i < n){
    float4 v = *(const float4*)(s + i);
    ushort4 o = make_ushort4(f2bf(v.x), f2bf(v.y), f2bf(v.z), f2bf(v.w));
    *(ushort4*)(d + i) = o;
  }
}

__global__ __launch_bounds__(256) void bias_sum_k(const float* __restrict__ a,
                                                  const float* __restrict__ b,
                                                  float* __restrict__ o){
  int i = blockIdx.x*256 + threadIdx.x;
  if (i < 1024) o[i] = a[i] + b[i];
}

// fused bias: o[n] = sum_k b_in[k]*W[k][n] + b_out[n]
__global__ __launch_bounds__(256) void fuse_bias(const float* __restrict__ b_in,
                                                 const float* __restrict__ W,
                                                 const float* __restrict__ b_out,
                                                 float* __restrict__ o, int K, int N){
  int n = blockIdx.x*256 + threadIdx.x;
  if (n < N){
    float s = b_out[n];
    for (int k=0;k<K;++k) s += b_in[k]*W[(size_t)k*N + n];
    o[n] = s;
  }
}

// ---------------- RMSNorm: f32 in -> bf16 out ----------------
__global__ __launch_bounds__(256) void rms_kernel(const float* __restrict__ x,
                                                  const float* __restrict__ scale,
                                                  ushort* __restrict__ out){
  int row = blockIdx.x, t = threadIdx.x;
  const float* xr = x + (size_t)row*1024;
  float4 v = *(const float4*)(xr + t*4);
  float ss = v.x*v.x + v.y*v.y + v.z*v.z + v.w*v.w;
  #pragma unroll
  for (int o=1;o<64;o<<=1) ss += __shfl_xor(ss, o);
  __shared__ float wsum[4];
  if ((t & 63)==0) wsum[t>>6] = ss;
  __syncthreads();
  float tot = wsum[0]+wsum[1]+wsum[2]+wsum[3];
  float rstd = rsqrtf(tot*(1.f/1024.f) + 1e-6f);
  float4 sc = *(const float4*)(scale + t*4);
  ushort4 o4 = make_ushort4(f2bf(v.x*sc.x*rstd), f2bf(v.y*sc.y*rstd),
                            f2bf(v.z*sc.z*rstd), f2bf(v.w*sc.w*rstd));
  *(ushort4*)(out + (size_t)row*1024 + t*4) = o4;
}

// ---------------- GEMM (global_load_lds staging) ----------------
template<int EPI>
__global__ __launch_bounds__(256,2) void gemm_bf16(
    const ushort* __restrict__ A, const ushort* __restrict__ Bt,
    const float* __restrict__ bias, void* __restrict__ Cout,
    const void* __restrict__ aux0, const void* __restrict__ aux1,
    int M, int N, int K)
{
  __shared__ ushort Al[128*32];
  __shared__ ushort Bl[128*32];
  const int t = threadIdx.x, ln = t & 63;
  const int m0 = blockIdx.y*128, n0 = blockIdx.x*128;
  const int wv = t >> 6, wr = wv >> 1, wc = wv & 1;
  const int lr = ln & 15, lk = ln >> 4;
  f32x4 acc[4][4] = {};
  for (int kk = 0; kk < K; kk += 32) {
    #pragma unroll
    for (int cc = 0; cc < 2; ++cc) {
      int e = cc*256 + t;
      int r = e >> 2, sg = e & 3;
      __builtin_amdgcn_global_load_lds((const uint*)(A  + (size_t)(m0+r)*K + kk + sg*8),
                                       (uint*)&Al[e*8], 16, 0, 0);
      __builtin_amdgcn_global_load_lds((const uint*)(Bt + (size_t)(n0+r)*K + kk + sg*8),
                                       (uint*)&Bl[e*8], 16, 0, 0);
    }
    __syncthreads();
    s16x8 af[4], bfr[4];
    #pragma unroll
    for (int m=0;m<4;++m) af[m]  = *(const s16x8*)&Al[(wr*64 + m*16 + lr)*32 + lk*8];
    #pragma unroll
    for (int n=0;n<4;++n) bfr[n] = *(const s16x8*)&Bl[(wc*64 + n*16 + lr)*32 + lk*8];
    #pragma unroll
    for (int m=0;m<4;++m)
      #pragma unroll
      for (int n=0;n<4;++n)
        acc[m][n] = mfma16(af[m], bfr[n], acc[m][n]);
    __syncthreads();
  }
  #pragma unroll
  for (int m=0;m<4;++m){
    #pragma unroll
    for (int n=0;n<4;++n){
      #pragma unroll
      for (int j=0;j<4;++j){
        int row = m0 + wr*64 + m*16 + lk*4 + j;
        int col = n0 + wc*64 + n*16 + lr;
        float v = acc[m][n][j] + (bias ? bias[col] : 0.f);
        size_t idx = (size_t)row*N + col;
        if constexpr (EPI==0){ ((ushort*)Cout)[idx] = f2bf(v); }
        else if constexpr (EPI==1){ ((ushort*)Cout)[idx] = f2bf(fgelu(v)); }
        else if constexpr (EPI==2){ ((ushort*)Cout)[idx] = f2bf(fsigmoid(v)); }
        else if constexpr (EPI==3){
          float g = fsigmoid(v) * bf2f(((const ushort*)aux0)[idx]);
          g = fminf(fmaxf(g, 1e-6f), 1.f-1e-6f);
          ((ushort*)Cout)[idx] = f2bf(g);
        }
        else if constexpr (EPI==4){
          float o = v + ((const float*)aux0)[idx] + 0.1f*bf2f(((const ushort*)aux1)[idx]);
          ((float*)Cout)[idx] = o;
        }
        else if constexpr (EPI==5){ ((float*)Cout)[idx] += v; }
        else if constexpr (EPI==6){
          int bb = row >> 9, mm = row & 511, hh = col >> 7, dd = col & 127;
          ((ushort*)Cout)[ (((size_t)(bb*8 + hh)*128 + dd) << 9) + mm ] = f2bf(v);
        }
        else if constexpr (EPI==7){
          ((ushort*)Cout)[(size_t)col*M + row] = f2bf(v);
        }
      }
    }
  }
}

// ---------------- memory attention ----------------
__global__ __launch_bounds__(256,1) void attn_kernel(
  const ushort* __restrict__ qh, const ushort* __restrict__ kh,
  const ushort* __restrict__ vhT, ushort* __restrict__ att)
{
  __shared__ ushort P[4*16*512];
  const int t = threadIdx.x, ln = t & 63, wv = t >> 6;
  const int lr = ln & 15, lk = ln >> 4;
  const int b = blockIdx.z, h = blockIdx.y, s0 = blockIdx.x*64;

  const ushort* qrow = qh + (size_t)(b*4096 + s0 + wv*16 + lr)*1024 + h*128 + lk*8;
  s16x8 qf[4];
  #pragma unroll
  for (int kt=0;kt<4;++kt) qf[kt] = *(const s16x8*)(qrow + kt*32);
  __syncthreads();

  f32x4 zero4 = {0.f,0.f,0.f,0.f};
  f32x4 sacc[32];
  #pragma unroll
  for (int i=0;i<32;++i) sacc[i] = zero4;

  const ushort* kbase = kh + (size_t)(b*512)*1024 + h*128 + lk*8;
  #pragma unroll
  for (int mt=0;mt<32;++mt){
    const ushort* krow = kbase + (size_t)(mt*16 + lr)*1024;
    #pragma unroll
    for (int kt=0;kt<4;++kt){
      s16x8 kf = *(const s16x8*)(krow + kt*32);
      sacc[mt] = mfma16(qf[kt], kf, sacc[mt]);
    }
  }
  const float scale = 0.08838834764831845f;
  float inv[4];
  #pragma unroll
  for (int j=0;j<4;++j){
    float m = -3.4e38f;
    #pragma unroll
    for (int mt=0;mt<32;++mt) m = fmaxf(m, sacc[mt][j]);
    m = fmaxf(m, __shfl_xor(m,1)); m = fmaxf(m, __shfl_xor(m,2));
    m = fmaxf(m, __shfl_xor(m,4)); m = fmaxf(m, __shfl_xor(m,8));
    float s = 0.f;
    #pragma unroll
    for (int mt=0;mt<32;++mt){
      float p = __expf((sacc[mt][j]-m)*scale);
      sacc[mt][j] = p; s += p;
    }
    s += __shfl_xor(s,1); s += __shfl_xor(s,2);
    s += __shfl_xor(s,4); s += __shfl_xor(s,8);
    inv[j] = 1.f/s;
  }
  char* pb = (char*)P + wv*16384;
  #pragma unroll
  for (int j=0;j<4;++j){
    int row = lk*4 + j;
    uint xr = (uint)((row & 7) << 4);
    #pragma unroll
    for (int mt=0;mt<32;++mt){
      int col = mt*16 + lr;
      *(ushort*)(pb + row*1024 + (((uint)(col*2)) ^ xr)) = f2bf(sacc[mt][j]);
    }
  }
  f32x4 oacc[8];
  #pragma unroll
  for (int i=0;i<8;++i) oacc[i] = zero4;
  const ushort* vb = vhT + (size_t)(b*8 + h)*128*512;
  const char* prow = (char*)P + wv*16384 + lr*1024;
  uint xrr = (uint)((lr & 7) << 4);
  #pragma unroll
  for (int km=0;km<16;++km){
    s16x8 pf = *(const s16x8*)(prow + (((uint)((km*32 + lk*8)*2)) ^ xrr));
    #pragma unroll
    for (int dt=0;dt<8;++dt){
      s16x8 vf = *(const s16x8*)(vb + (size_t)(dt*16 + lr)*512 + km*32 + lk*8);
      oacc[dt] = mfma16(pf, vf, oacc[dt]);
    }
  }
  ushort* ob = att + (size_t)(b*4096 + s0 + wv*16)*1024 + h*128;
  #pragma unroll
  for (int dt=0;dt<8;++dt){
    #pragma unroll
    for (int j=0;j<4;++j){
      int row = lk*4 + j, col = dt*16 + lr;
      ob[(size_t)row*1024 + col] = f2bf(oacc[dt][j]*inv[j]);
    }
  }
}

// ================= MEGA: scan (blocks 0-63) + pipelined FFN (blocks 64-255) ==============
// Scan identical to r12 (tagged sc0sc1 exchange) + coherent xres stores + final tag 4098.
// FFN workers poll h tags (tag T => xres steps <= T-2 visible), consume 32-row tiles from
// an atomic queue: RMS -> xn2(LDS) -> 4x{FFN1 chunk -> gelu -> LDS -> FFN2 accum} -> out.
// 132KB LDS => 1 block/CU => all 256 blocks resident (no dispatch deadlock).
#define SCAN_NB 64
__global__ __launch_bounds__(256,1) void scan_ffn_kernel(
  const float* __restrict__ Wgh,
  const ushort* __restrict__ u_bf, const ushort* __restrict__ z_bf,
  const ushort* __restrict__ g_bf, float* __restrict__ xres,
  unsigned long long* __restrict__ h_buf, uint* __restrict__ queue,
  const ushort* __restrict__ Wf1T, const ushort* __restrict__ Wf2Tc,
  const float* __restrict__ bf1, const float* __restrict__ bf2,
  const float* __restrict__ n2s)
{
  __shared__ __align__(16) char SM[132352];
  const int t = threadIdx.x;

  if (blockIdx.x < SCAN_NB) {
    // ================= SCAN =================
    ushort* WL = (ushort*)SM;            // [16][1032]
    ushort* HL = (ushort*)(SM + 33024);  // [5][1032]
    float (*red)[16][4] = (float(*)[16][4])(SM + 43344);
    const int blk = blockIdx.x, ln = t & 63, wv = t >> 6;
    {
      const int c = t & 15, i0q = (t >> 4) * 64;
      for (int j = 0; j < 64; ++j) {
        int i = i0q + j;
        WL[c*1032 + i] = f2bf(Wgh[(size_t)i*1024 + blk*16 + c]);
      }
    }
    for (int e = t; e < 1032; e += 256) HL[4*1032 + e] = 0;

    float hmine = 0.f;
    const int c_ep = t & 15, b_ep = t >> 4;
    float uu=0.f, zz=0.f, gg=0.f, xv=0.f;
    if (t < 64) {
      size_t i0 = ((size_t)(b_ep*4096))*1024 + blk*16 + c_ep;
      uu = bf2f(u_bf[i0]); zz = bf2f(z_bf[i0]); gg = bf2f(g_bf[i0]); xv = xres[i0];
    }
    __syncthreads();

    const int arow = ln & 15, akc = ln >> 4;
    const ushort* Abase = &HL[(arow < 4 ? arow : 4)*1032 + akc*8];
    const ushort* Bbase = &WL[(ln & 15)*1032 + akc*8];
    const int hb_t = t >> 6, hk0 = (t & 63)*16;

    for (int step = 0; step < 4096; ++step) {
      {
        const unsigned long long* hs = h_buf + (size_t)(step & 1)*2048 + t*8;
        u32x4 r0, r1, r2, r3;
        while (true) {
          load8_u64_coherent(hs, r0, r1, r2, r3);
          uint st = (uint)step;
          if (r0.y==st && r0.w==st && r1.y==st && r1.w==st &&
              r2.y==st && r2.w==st && r3.y==st && r3.w==st) break;
        }
        uint* dst = (uint*)&HL[hb_t*1032 + hk0];
        *(uint4*)(dst + 0) = make_uint4(r0.x, r0.z, r1.x, r1.z);
        *(uint4*)(dst + 4) = make_uint4(r2.x, r2.z, r3.x, r3.z);
      }
      __syncthreads();
      f32x4 acc = {0.f,0.f,0.f,0.f};
      #pragma unroll
      for (int m = 0; m < 8; ++m) {
        int koff = wv*256 + m*32;
        s16x8 a = *(const s16x8*)(Abase + koff);
        s16x8 b = *(const s16x8*)(Bbase + koff);
        acc = mfma16(a, b, acc);
      }
      if (ln < 16) *(f32x4*)&red[wv][ln][0] = acc;
      __syncthreads();
      if (t < 64) {
        float y = red[0][c_ep][b_ep] + red[1][c_ep][b_ep]
                + red[2][c_ep][b_ep] + red[3][c_ep][b_ep];
        float gate = fsigmoid(y + uu);
        float hn = hmine + gate*(zz - hmine) + gg*hmine;
        hmine = hn;
        int colg = blk*16 + c_ep;
        float hup = __shfl_down(hn, 1);
        if ((t & 1) == 0) {
          unsigned long long pk = ((unsigned long long)(uint)(step+1) << 32)
                                | ((uint)f2bf(hup) << 16) | (uint)f2bf(hn);
          store_u64_coherent(h_buf + (size_t)((step+1)&1)*2048 + b_ep*512 + (colg>>1), pk);
        }
        size_t idx = ((size_t)(b_ep*4096 + step))*1024 + colg;
        store_f32_coherent(&xres[idx], xv + hn);
        int sn = (step+1 < 4096) ? step+1 : 4095;
        size_t idxn = ((size_t)(b_ep*4096 + sn))*1024 + colg;
        uu = bf2f(u_bf[idxn]); zz = bf2f(z_bf[idxn]); gg = bf2f(g_bf[idxn]);
        xv = xres[idxn];
      }
    }
    // final tag: all xres stores drained, then publish 4098 (parity-0 words)
    asm volatile("s_waitcnt vmcnt(0)" ::: "memory");
    if (t < 64 && (t & 1) == 0) {
      store_u64_coherent(h_buf + (size_t)b_ep*512 + blk*8 + (c_ep>>1), 4098ULL << 32);
    }
    return;
  }

  // ================= FFN WORKER =================
  ushort* Aq = (ushort*)SM;            // xn2 tile [32][1032] bf16
  ushort* Fq = (ushort*)(SM + 66048);  // f1 chunk [32][1032] bf16
  float*  XT = (float*)SM;             // xres tile [32][1024] f32 (reuses Aq+Fq region)
  int* tileslot = (int*)(SM + 132096);
  const int ln = t & 63, w = t >> 6;
  const int lr = ln & 15, lk = ln >> 4;

  for (;;) {
    if (t == 0) *tileslot = (int)atomicAdd(queue, 1u);
    __syncthreads();
    const int tk = *tileslot;
    __syncthreads();
    if (tk >= 512) break;
    const int s0 = (tk >> 2)*32, b = tk & 3;
    const size_t rowbase = (size_t)b*4096 + s0;

    // ---- wait until scan progress covers rows [s0, s0+32) with slack ----
    if (w == 0) {
      const int vt = s0 + 34;   // even => parity-0 slot; max 4098 (final tag)
      const unsigned long long* pw = h_buf + (size_t)b*512 + ln*8;
      while (true) {
        unsigned long long v = load_u64_coherent(pw);
        if (__all((int)((uint)(v >> 32) >= (uint)vt))) break;
        __builtin_amdgcn_s_sleep(8);
      }
    }
    __syncthreads();

    // ---- RMS: coherent read 32x1024 xres, xn2 bf16 -> Aq ----
    {
      const int r8 = t >> 3, p8 = t & 7;
      const float* xrow = xres + (rowbase + r8)*1024 + p8*128;
      f32x4 va[4][8];
      load8x16_coh(xrow +  0, va[0]);
      load8x16_coh(xrow + 32, va[1]);
      load8x16_coh(xrow + 64, va[2]);
      load8x16_coh(xrow + 96, va[3]);
      float ss = 0.f;
      #pragma unroll
      for (int g=0; g<4; ++g)
        #pragma unroll
        for (int i=0; i<8; ++i)
          ss += va[g][i][0]*va[g][i][0] + va[g][i][1]*va[g][i][1]
              + va[g][i][2]*va[g][i][2] + va[g][i][3]*va[g][i][3];
      ss += __shfl_xor(ss,1); ss += __shfl_xor(ss,2); ss += __shfl_xor(ss,4);
      float rstd = rsqrtf(ss*(1.f/1024.f) + 1e-6f);
      #pragma unroll
      for (int g=0; g<4; ++g)
        #pragma unroll
        for (int i=0; i<8; ++i) {
          int c = p8*128 + g*32 + i*4;
          float4 sc4 = *(const float4*)(n2s + c);
          ushort4 o4 = make_ushort4(f2bf(va[g][i][0]*sc4.x*rstd),
                                    f2bf(va[g][i][1]*sc4.y*rstd),
                                    f2bf(va[g][i][2]*sc4.z*rstd),
                                    f2bf(va[g][i][3]*sc4.w*rstd));
          *(ushort4*)&Aq[r8*1032 + c] = o4;
        }
    }
    __syncthreads();

    // ---- 4 chunks: FFN1 (xn2 @ Wf1T chunk, gelu) -> Fq; FFN2 accum (Fq @ Wf2Tc) ----
    f32x4 acc2[2][16] = {};
    for (int nc = 0; nc < 4; ++nc) {
      f32x4 acc1[2][16] = {};
      const ushort* Bp1 = Wf1T + ((size_t)(nc*1024 + w*256 + lr))*1024 + lk*8;
      for (int kk = 0; kk < 32; ++kk) {
        s16x8 a0 = *(const s16x8*)&Aq[lr*1032 + kk*32 + lk*8];
        s16x8 a1 = *(const s16x8*)&Aq[(16+lr)*1032 + kk*32 + lk*8];
        #pragma unroll
        for (int ct = 0; ct < 16; ++ct) {
          s16x8 bf = *(const s16x8*)(Bp1 + (size_t)ct*16*1024 + kk*32);
          acc1[0][ct] = mfma16(a0, bf, acc1[0][ct]);
          acc1[1][ct] = mfma16(a1, bf, acc1[1][ct]);
        }
      }
      #pragma unroll
      for (int ct = 0; ct < 16; ++ct) {
        int colc = w*256 + ct*16 + lr;
        float bb = bf1[nc*1024 + colc];
        #pragma unroll
        for (int rg = 0; rg < 2; ++rg)
          #pragma unroll
          for (int j = 0; j < 4; ++j) {
            int rowl = rg*16 + lk*4 + j;
            Fq[rowl*1032 + colc] = f2bf(fgelu(acc1[rg][ct][j] + bb));
          }
      }
      __syncthreads();
      const ushort* Bp2 = Wf2Tc + (size_t)nc*1048576 + ((size_t)(w*256 + lr))*1024 + lk*8;
      for (int kk = 0; kk < 32; ++kk) {
        s16x8 a0 = *(const s16x8*)&Fq[lr*1032 + kk*32 + lk*8];
        s16x8 a1 = *(const s16x8*)&Fq[(16+lr)*1032 + kk*32 + lk*8];
        #pragma unroll
        for (int ot = 0; ot < 16; ++ot) {
          s16x8 bf = *(const s16x8*)(Bp2 + (size_t)ot*16*1024 + kk*32);
          acc2[0][ot] = mfma16(a0, bf, acc2[0][ot]);
          acc2[1][ot] = mfma16(a1, bf, acc2[1][ot]);
        }
      }
      __syncthreads();
    }

    // ---- coherent re-read xres tile into XT (Aq/Fq dead) ----
    {
      const int r8 = t >> 3, p8 = t & 7;
      const float* xrow = xres + (rowbase + r8)*1024 + p8*128;
      #pragma unroll
      for (int g=0; g<4; ++g) {
        f32x4 vb[8];
        load8x16_coh(xrow + g*32, vb);
        #pragma unroll
        for (int i=0; i<8; ++i)
          *(f32x4*)&XT[r8*1024 + p8*128 + g*32 + i*4] = vb[i];
      }
    }
    __syncthreads();
    // ---- epilogue: out = xres + bf2 + ffn2 ----
    #pragma unroll
    for (int ot = 0; ot < 16; ++ot) {
      int col = w*256 + ot*16 + lr;
      float bb = bf2[col];
      #pragma unroll
      for (int rg = 0; rg < 2; ++rg)
        #pragma unroll
        for (int j = 0; j < 4; ++j) {
          int rowl = rg*16 + lk*4 + j;
          xres[(rowbase + rowl)*1024 + col] = XT[rowl*1024 + col] + bb + acc2[rg][ot][j];
        }
    }
    __syncthreads();
  }
}

// =======================================================================================
extern "C" void kernel_launch(void* const* d_in, const int* in_sizes, int n_in,
                              void* d_out, int out_size, void* d_ws, size_t ws_size,
                              hipStream_t stream)
{
  const float* x    = (const float*)d_in[0];
  const float* memk = (const float*)d_in[1];
  const float* memv = (const float*)d_in[2];
  const float* n1s  = (const float*)d_in[3];
  const float* n2s  = (const float*)d_in[4];
  const float* Wq = (const float*)d_in[5];   const float* bq = (const float*)d_in[6];
  const float* Wk = (const float*)d_in[7];   const float* bk = (const float*)d_in[8];
  const float* Wv = (const float*)d_in[9];   const float* bv = (const float*)d_in[10];
  const float* Wz = (const float*)d_in[11];  const float* bz = (const float*)d_in[12];
  const float* Wgz = (const float*)d_in[13]; const float* bgz = (const float*)d_in[14];
  const float* Wgh = (const float*)d_in[15]; const float* bgh = (const float*)d_in[16];
  const float* Wg1 = (const float*)d_in[17]; const float* bg1 = (const float*)d_in[18];
  const float* Wg2 = (const float*)d_in[19]; const float* bg2 = (const float*)d_in[20];
  const float* Wgc1 = (const float*)d_in[21]; const float* bgc1 = (const float*)d_in[22];
  const float* Wgc2 = (const float*)d_in[23]; const float* bgc2 = (const float*)d_in[24];
  const float* Awq = (const float*)d_in[25]; const float* abq = (const float*)d_in[26];
  const float* Awk = (const float*)d_in[27]; const float* abk = (const float*)d_in[28];
  const float* Awv = (const float*)d_in[29]; const float* abv = (const float*)d_in[30];
  const float* Awo = (const float*)d_in[31]; const float* abo = (const float*)d_in[32];
  const float* Wf1 = (const float*)d_in[33]; const float* bf1 = (const float*)d_in[34];
  const float* Wf2 = (const float*)d_in[35]; const float* bf2 = (const float*)d_in[36];
  (void)in_sizes; (void)n_in; (void)out_size; (void)ws_size;

  char* ws = (char*)d_ws;
  constexpr size_t MB = 1ull<<20;
  ushort* WvT     = (ushort*)(ws + 0*MB);
  ushort* WzT     = (ushort*)(ws + 2*MB);
  ushort* WgzT    = (ushort*)(ws + 4*MB);
  ushort* WqAwqT  = (ushort*)(ws + 6*MB);
  ushort* AwkT    = (ushort*)(ws + 8*MB);
  ushort* AwvT    = (ushort*)(ws + 10*MB);
  ushort* AwoT    = (ushort*)(ws + 12*MB);
  ushort* Wf1T    = (ushort*)(ws + 14*MB);            // [4096][1024]
  ushort* Wf2Tc   = (ushort*)(ws + 22*MB);            // 4 x [1024][1024]
  ushort* Wg1T    = (ushort*)(ws + 30*MB);
  ushort* Wg2T    = (ushort*)(ws + 30*MB + 512*1024);
  ushort* Wgc2T   = (ushort*)(ws + 31*MB);
  ushort* WkWgc1T = (ushort*)(ws + 31*MB + 512*1024);
  float* bsum = (float*)(ws + 32*MB);
  float* bqh  = (float*)(ws + 32*MB + 4096);
  float* bkg  = (float*)(ws + 32*MB + 8192);
  char*  scanB = ws + 32*MB + 65536;  // h_buf 32KB + queue
  ushort* Abuf = (ushort*)(ws + 33*MB);
  ushort* Bbuf = (ushort*)(ws + 65*MB);
  ushort* Cbuf = (ushort*)(ws + 97*MB);
  ushort* Dbuf = (ushort*)(ws + 129*MB);
  ushort* Ebuf = (ushort*)(ws + 161*MB);
  char* db = (char*)d_out;
  ushort* t1B   = (ushort*)(db + 0);
  ushort* memkB = (ushort*)(db + 8*MB);
  ushort* memvB = (ushort*)(db + 12*MB);
  ushort* khB   = (ushort*)(db + 16*MB);
  ushort* vhTB  = (ushort*)(db + 20*MB);
  ushort* gbB   = (ushort*)(db + 24*MB);
  ushort* WtmpB = (ushort*)(db + 56*MB);
  ushort* BtTB  = (ushort*)(db + 58*MB);

  const int M1 = 16384;
  dim3 b256(256);
  auto T = [&](const float* s, ushort* d, int K, int N){
    transpose_cvt<<<dim3(N/64, K/64), b256, 0, stream>>>(s, d, K, N);
  };
  #define G(EPI, Ap, Bp, bi, Cp, a0, a1, Mv, Nv, Kv) \
    gemm_bf16<EPI><<<dim3((Nv)/128,(Mv)/128), b256, 0, stream>>>( \
      (const ushort*)(Ap), (const ushort*)(Bp), bi, (void*)(Cp), a0, a1, Mv, Nv, Kv)

  // ---- fused weights ----
  cvt_bf16<<<1024, b256, 0, stream>>>(Wq, WtmpB, 1048576);
  T(Awq, BtTB, 1024, 1024);
  G(7, WtmpB, BtTB, nullptr, WqAwqT, nullptr, nullptr, 1024, 1024, 1024);
  fuse_bias<<<4, b256, 0, stream>>>(bq, Awq, abq, bqh, 1024, 1024);
  cvt_bf16<<<1024, b256, 0, stream>>>(Wk, WtmpB, 1048576);
  T(Wgc1, BtTB, 1024, 256);
  G(7, WtmpB, BtTB, nullptr, WkWgc1T, nullptr, nullptr, 1024, 256, 1024);
  fuse_bias<<<1, b256, 0, stream>>>(bk, Wgc1, bgc1, bkg, 1024, 256);
  // ---- plain transposed weights ----
  T(Wv,WvT,1024,1024); T(Wz,WzT,1024,1024); T(Wgz,WgzT,1024,1024);
  T(Wg1,Wg1T,1024,256); T(Wg2,Wg2T,256,1024); T(Wgc2,Wgc2T,256,1024);
  T(Awk,AwkT,1024,1024); T(Awv,AwvT,1024,1024); T(Awo,AwoT,1024,1024);
  T(Wf1,Wf1T,1024,4096);
  for (int cch = 0; cch < 4; ++cch)
    T(Wf2 + (size_t)cch*1048576, Wf2Tc + (size_t)cch*1048576, 1024, 1024);
  bias_sum_k<<<4, b256, 0, stream>>>(bgz, bgh, bsum);
  cvt_bf16<<<2048, b256, 0, stream>>>(memk, memkB, 2097152);
  cvt_bf16<<<2048, b256, 0, stream>>>(memv, memvB, 2097152);

  // ---- forward ----
  rms_kernel<<<M1, b256, 0, stream>>>(x, n1s, Abuf);                    // xn
  G(0, Abuf, WzT, bz, Bbuf, nullptr, nullptr, M1, 1024, 1024);          // z
  G(0, Abuf, WvT, bv, Cbuf, nullptr, nullptr, M1, 1024, 1024);          // v
  G(0, Abuf, WqAwqT, bqh, Dbuf, nullptr, nullptr, M1, 1024, 1024);      // qh
  G(0, Bbuf, WgzT, bsum, Ebuf, nullptr, nullptr, M1, 1024, 1024);       // u
  G(1, Bbuf, Wg1T, bg1, t1B, nullptr, nullptr, M1, 256, 1024);          // t1z
  G(2, t1B, Wg2T, bg2, gbB, nullptr, nullptr, M1, 1024, 256);           // gamma_base
  G(1, Abuf, WkWgc1T, bkg, t1B, nullptr, nullptr, M1, 256, 1024);       // t1k
  G(3, t1B, Wgc2T, bgc2, Abuf, gbB, nullptr, M1, 1024, 256);            // gamma
  G(0, memkB, AwkT, abk, khB, nullptr, nullptr, 2048, 1024, 1024);      // kh
  G(6, memvB, AwvT, abv, vhTB, nullptr, nullptr, 2048, 1024, 1024);     // vhT
  attn_kernel<<<dim3(64,8,4), b256, 0, stream>>>(Dbuf, khB, vhTB, Dbuf);
  G(4, Dbuf, AwoT, abo, d_out, (const void*)x, (const void*)Cbuf, M1, 1024, 1024);
  hipMemsetAsync(scanB, 0, 36864, stream);
  scan_ffn_kernel<<<256, b256, 0, stream>>>(Wgh, Ebuf, Bbuf, Abuf, (float*)d_out,
                                            (unsigned long long*)scanB,
                                            (uint*)(scanB + 32768),
                                            Wf1T, Wf2Tc, bf1, bf2, n2s);
  #undef G
}

// Round 14
// 12041.599 us; speedup vs baseline: 1.0738x; 1.0738x over previous
//
#include <hip/hip_runtime.h>
#include <stdint.h>

typedef short s16x8 __attribute__((ext_vector_type(8)));
typedef float f32x4 __attribute__((ext_vector_type(4)));
typedef uint  u32x4 __attribute__((ext_vector_type(4)));

#define DEV static __device__ __forceinline__

DEV float bf2f(ushort u){ union{uint i;float f;}v; v.i=((uint)u)<<16; return v.f; }
DEV ushort f2bf(float f){ union{float f;uint i;}v; v.f=f; return (ushort)((v.i + 0x7FFFu + ((v.i>>16)&1u))>>16); }
DEV float fsigmoid(float x){ return 1.f/(1.f+__expf(-x)); }
DEV float fgelu(float x){
  float u = 0.7978845608028654f*(x + 0.044715f*x*x*x);
  float e = __expf(2.f*u);
  float th = 1.f - 2.f/(e+1.f);   // tanh(u), stable
  return 0.5f*x*(1.f+th);
}
DEV f32x4 mfma16(s16x8 a, s16x8 b, f32x4 c){
  return __builtin_amdgcn_mfma_f32_16x16x32_bf16(a,b,c,0,0,0);
}

// coherent (L1+L2-bypass) 64-bit store to the device coherence point
DEV void store_u64_coherent(unsigned long long* p, unsigned long long v){
  asm volatile("global_store_dwordx2 %0, %1, off sc0 sc1" :: "v"(p), "v"(v) : "memory");
}
// coherent batched load of 8 consecutive u64 words (4 x dwordx4), self-waiting
DEV void load8_u64_coherent(const unsigned long long* p, u32x4& r0, u32x4& r1,
                            u32x4& r2, u32x4& r3){
  asm volatile("global_load_dwordx4 %0, %4, off sc0 sc1\n\t"
               "global_load_dwordx4 %1, %4, off offset:16 sc0 sc1\n\t"
               "global_load_dwordx4 %2, %4, off offset:32 sc0 sc1\n\t"
               "global_load_dwordx4 %3, %4, off offset:48 sc0 sc1\n\t"
               "s_waitcnt vmcnt(0)"
               : "=&v"(r0), "=&v"(r1), "=&v"(r2), "=&v"(r3)
               : "v"(p) : "memory");
}

// ---------------- transpose + f32->bf16 convert: dst[N][K] = bf16(src[K][N]) ----------------
__global__ __launch_bounds__(256) void transpose_cvt(const float* __restrict__ src,
                                                     ushort* __restrict__ dst, int K, int N){
  __shared__ float tile[64][65];
  int tk = blockIdx.y*64, tn = blockIdx.x*64;
  int t = threadIdx.x;
  int c4 = (t & 15)*4, r0 = t >> 4;
  #pragma unroll
  for (int p=0;p<4;++p){
    int r = r0 + p*16;
    float4 v = *(const float4*)(src + (size_t)(tk+r)*N + tn + c4);
    tile[r][c4+0]=v.x; tile[r][c4+1]=v.y; tile[r][c4+2]=v.z; tile[r][c4+3]=v.w;
  }
  __syncthreads();
  #pragma unroll
  for (int p=0;p<4;++p){
    int n = r0 + p*16;
    ushort4 o = make_ushort4(f2bf(tile[c4+0][n]), f2bf(tile[c4+1][n]),
                             f2bf(tile[c4+2][n]), f2bf(tile[c4+3][n]));
    *(ushort4*)(dst + (size_t)(tn+n)*K + tk + c4) = o;
  }
}

// ---------------- elementwise f32->bf16 ----------------
__global__ __launch_bounds__(256) void cvt_bf16(const float* __restrict__ s,
                                                ushort* __restrict__ d, int n){
  int i = (blockIdx.x*256 + threadIdx.x)*4;
  if (i < n){
    float4 v = *(const float4*)(s + i);
    ushort4 o = make_ushort4(f2bf(v.x), f2bf(v.y), f2bf(v.z), f2bf(v.w));
    *(ushort4*)(d + i) = o;
  }
}

__global__ __launch_bounds__(256) void bias_sum_k(const float* __restrict__ a,
                                                  const float* __restrict__ b,
                                                  float* __restrict__ o){
  int i = blockIdx.x*256 + threadIdx.x;
  if (i < 1024) o[i] = a[i] + b[i];
}

// fused bias: o[n] = sum_k b_in[k]*W[k][n] + b_out[n]
__global__ __launch_bounds__(256) void fuse_bias(const float* __restrict__ b_in,
                                                 const float* __restrict__ W,
                                                 const float* __restrict__ b_out,
                                                 float* __restrict__ o, int K, int N){
  int n = blockIdx.x*256 + threadIdx.x;
  if (n < N){
    float s = b_out[n];
    for (int k=0;k<K;++k) s += b_in[k]*W[(size_t)k*N + n];
    o[n] = s;
  }
}

// ---------------- RMSNorm: f32 in -> bf16 out (does not modify input) ----------------
__global__ __launch_bounds__(256) void rms_kernel(const float* __restrict__ x,
                                                  const float* __restrict__ scale,
                                                  ushort* __restrict__ out){
  int row = blockIdx.x, t = threadIdx.x;
  const float* xr = x + (size_t)row*1024;
  float4 v = *(const float4*)(xr + t*4);
  float ss = v.x*v.x + v.y*v.y + v.z*v.z + v.w*v.w;
  #pragma unroll
  for (int o=1;o<64;o<<=1) ss += __shfl_xor(ss, o);
  __shared__ float wsum[4];
  if ((t & 63)==0) wsum[t>>6] = ss;
  __syncthreads();
  float tot = wsum[0]+wsum[1]+wsum[2]+wsum[3];
  float rstd = rsqrtf(tot*(1.f/1024.f) + 1e-6f);
  float4 sc = *(const float4*)(scale + t*4);
  ushort4 o4 = make_ushort4(f2bf(v.x*sc.x*rstd), f2bf(v.y*sc.y*rstd),
                            f2bf(v.z*sc.z*rstd), f2bf(v.w*sc.w*rstd));
  *(ushort4*)(out + (size_t)row*1024 + t*4) = o4;
}

// ---------------- GEMM: C = epi(A[M][K](bf16) @ Bt[N][K](bf16)^T + bias) ----------------
// Staging via global_load_lds (16B/lane, linear-in-lane LDS layout — m97 pattern).
// EPI: 0 bf16  1 gelu->bf16  2 sigmoid->bf16  3 clip(sigmoid*aux0)->bf16
//      4 f32 = v + aux0_f32 + 0.1*aux1_bf16   5 f32 +=   6 bf16 scattered vhT
//      7 bf16 transposed store [col*M+row]
template<int EPI>
__global__ __launch_bounds__(256,2) void gemm_bf16(
    const ushort* __restrict__ A, const ushort* __restrict__ Bt,
    const float* __restrict__ bias, void* __restrict__ Cout,
    const void* __restrict__ aux0, const void* __restrict__ aux1,
    int M, int N, int K)
{
  __shared__ ushort Al[128*32];
  __shared__ ushort Bl[128*32];
  const int t = threadIdx.x, ln = t & 63;
  const int m0 = blockIdx.y*128, n0 = blockIdx.x*128;
  const int wv = t >> 6, wr = wv >> 1, wc = wv & 1;
  const int lr = ln & 15, lk = ln >> 4;
  f32x4 acc[4][4] = {};
  for (int kk = 0; kk < K; kk += 32) {
    #pragma unroll
    for (int cc = 0; cc < 2; ++cc) {
      int e = cc*256 + t;
      int r = e >> 2, sg = e & 3;
      __builtin_amdgcn_global_load_lds((const uint*)(A  + (size_t)(m0+r)*K + kk + sg*8),
                                       (uint*)&Al[e*8], 16, 0, 0);
      __builtin_amdgcn_global_load_lds((const uint*)(Bt + (size_t)(n0+r)*K + kk + sg*8),
                                       (uint*)&Bl[e*8], 16, 0, 0);
    }
    __syncthreads();
    s16x8 af[4], bfr[4];
    #pragma unroll
    for (int m=0;m<4;++m) af[m]  = *(const s16x8*)&Al[(wr*64 + m*16 + lr)*32 + lk*8];
    #pragma unroll
    for (int n=0;n<4;++n) bfr[n] = *(const s16x8*)&Bl[(wc*64 + n*16 + lr)*32 + lk*8];
    #pragma unroll
    for (int m=0;m<4;++m)
      #pragma unroll
      for (int n=0;n<4;++n)
        acc[m][n] = mfma16(af[m], bfr[n], acc[m][n]);
    __syncthreads();
  }
  #pragma unroll
  for (int m=0;m<4;++m){
    #pragma unroll
    for (int n=0;n<4;++n){
      #pragma unroll
      for (int j=0;j<4;++j){
        int row = m0 + wr*64 + m*16 + lk*4 + j;
        int col = n0 + wc*64 + n*16 + lr;
        float v = acc[m][n][j] + (bias ? bias[col] : 0.f);
        size_t idx = (size_t)row*N + col;
        if constexpr (EPI==0){ ((ushort*)Cout)[idx] = f2bf(v); }
        else if constexpr (EPI==1){ ((ushort*)Cout)[idx] = f2bf(fgelu(v)); }
        else if constexpr (EPI==2){ ((ushort*)Cout)[idx] = f2bf(fsigmoid(v)); }
        else if constexpr (EPI==3){
          float g = fsigmoid(v) * bf2f(((const ushort*)aux0)[idx]);
          g = fminf(fmaxf(g, 1e-6f), 1.f-1e-6f);
          ((ushort*)Cout)[idx] = f2bf(g);
        }
        else if constexpr (EPI==4){
          float o = v + ((const float*)aux0)[idx] + 0.1f*bf2f(((const ushort*)aux1)[idx]);
          ((float*)Cout)[idx] = o;
        }
        else if constexpr (EPI==5){ ((float*)Cout)[idx] += v; }
        else if constexpr (EPI==6){
          int bb = row >> 9, mm = row & 511, hh = col >> 7, dd = col & 127;
          ((ushort*)Cout)[ (((size_t)(bb*8 + hh)*128 + dd) << 9) + mm ] = f2bf(v);
        }
        else if constexpr (EPI==7){
          ((ushort*)Cout)[(size_t)col*M + row] = f2bf(v);
        }
      }
    }
  }
}

// ---------------- memory attention: per (b,h,s-tile 64), M=512, hd=128 -------------------
__global__ __launch_bounds__(256,1) void attn_kernel(
  const ushort* __restrict__ qh, const ushort* __restrict__ kh,
  const ushort* __restrict__ vhT, ushort* __restrict__ att)
{
  __shared__ ushort P[4*16*512];   // 64KB, per-wave 16x512 bf16, XOR-swizzled
  const int t = threadIdx.x, ln = t & 63, wv = t >> 6;
  const int lr = ln & 15, lk = ln >> 4;
  const int b = blockIdx.z, h = blockIdx.y, s0 = blockIdx.x*64;

  const ushort* qrow = qh + (size_t)(b*4096 + s0 + wv*16 + lr)*1024 + h*128 + lk*8;
  s16x8 qf[4];
  #pragma unroll
  for (int kt=0;kt<4;++kt) qf[kt] = *(const s16x8*)(qrow + kt*32);
  __syncthreads();   // all q reads complete before any in-place writes later

  f32x4 zero4 = {0.f,0.f,0.f,0.f};
  f32x4 sacc[32];
  #pragma unroll
  for (int i=0;i<32;++i) sacc[i] = zero4;

  const ushort* kbase = kh + (size_t)(b*512)*1024 + h*128 + lk*8;
  #pragma unroll
  for (int mt=0;mt<32;++mt){
    const ushort* krow = kbase + (size_t)(mt*16 + lr)*1024;
    #pragma unroll
    for (int kt=0;kt<4;++kt){
      s16x8 kf = *(const s16x8*)(krow + kt*32);
      sacc[mt] = mfma16(qf[kt], kf, sacc[mt]);
    }
  }
  const float scale = 0.08838834764831845f;  // 1/sqrt(128)
  float inv[4];
  #pragma unroll
  for (int j=0;j<4;++j){
    float m = -3.4e38f;
    #pragma unroll
    for (int mt=0;mt<32;++mt) m = fmaxf(m, sacc[mt][j]);
    m = fmaxf(m, __shfl_xor(m,1)); m = fmaxf(m, __shfl_xor(m,2));
    m = fmaxf(m, __shfl_xor(m,4)); m = fmaxf(m, __shfl_xor(m,8));
    float s = 0.f;
    #pragma unroll
    for (int mt=0;mt<32;++mt){
      float p = __expf((sacc[mt][j]-m)*scale);
      sacc[mt][j] = p; s += p;
    }
    s += __shfl_xor(s,1); s += __shfl_xor(s,2);
    s += __shfl_xor(s,4); s += __shfl_xor(s,8);
    inv[j] = 1.f/s;
  }
  char* pb = (char*)P + wv*16384;
  #pragma unroll
  for (int j=0;j<4;++j){
    int row = lk*4 + j;
    uint xr = (uint)((row & 7) << 4);
    #pragma unroll
    for (int mt=0;mt<32;++mt){
      int col = mt*16 + lr;
      *(ushort*)(pb + row*1024 + (((uint)(col*2)) ^ xr)) = f2bf(sacc[mt][j]);
    }
  }
  f32x4 oacc[8];
  #pragma unroll
  for (int i=0;i<8;++i) oacc[i] = zero4;
  const ushort* vb = vhT + (size_t)(b*8 + h)*128*512;
  const char* prow = (char*)P + wv*16384 + lr*1024;
  uint xrr = (uint)((lr & 7) << 4);
  #pragma unroll
  for (int km=0;km<16;++km){
    s16x8 pf = *(const s16x8*)(prow + (((uint)((km*32 + lk*8)*2)) ^ xrr));
    #pragma unroll
    for (int dt=0;dt<8;++dt){
      s16x8 vf = *(const s16x8*)(vb + (size_t)(dt*16 + lr)*512 + km*32 + lk*8);
      oacc[dt] = mfma16(pf, vf, oacc[dt]);
    }
  }
  ushort* ob = att + (size_t)(b*4096 + s0 + wv*16)*1024 + h*128;
  #pragma unroll
  for (int dt=0;dt<8;++dt){
    #pragma unroll
    for (int j=0;j<4;++j){
      int row = lk*4 + j, col = dt*16 + lr;
      ob[(size_t)row*1024 + col] = f2bf(oacc[dt][j]*inv[j]);
    }
  }
}

// ---------------- sequential gated scan: 64 blocks x 16 cols, MFMA matvec ----------------
// Cross-block sync: TAGGED DATA through the device coherence point (sc0 sc1 on both the
// producer store and the consumer polling loads). Word = (step_tag<<32) | bf16x2 payload.
#define SCAN_NB 64
__global__ __launch_bounds__(256,1) void scan_kernel(
  const float* __restrict__ Wgh,
  const ushort* __restrict__ u_bf, const ushort* __restrict__ z_bf,
  const ushort* __restrict__ g_bf, float* __restrict__ xres,
  unsigned long long* __restrict__ h_buf)
{
  __shared__ ushort WL[16*1032];   // W^T bf16 [c][k], stride 1032
  __shared__ ushort HL[5*1032];    // rows 0..3 = h batches (bf16), row 4 = zeros
  __shared__ float  red[4][16][4]; // [wave][c][b]
  const int t = threadIdx.x, blk = blockIdx.x;
  const int ln = t & 63, wv = t >> 6;

  // ---- load W slice (coalesced 64B groups), transpose to LDS bf16 ----
  {
    const int c = t & 15, i0q = (t >> 4) * 64;
    for (int j = 0; j < 64; ++j) {
      int i = i0q + j;
      WL[c*1032 + i] = f2bf(Wgh[(size_t)i*1024 + blk*16 + c]);
    }
  }
  for (int e = t; e < 1032; e += 256) HL[4*1032 + e] = 0;  // zero row

  float hmine = 0.f;
  const int c_ep = t & 15, b_ep = t >> 4;   // valid t<64
  float uu=0.f, zz=0.f, gg=0.f, xv=0.f;
  if (t < 64) {
    size_t i0 = ((size_t)(b_ep*4096))*1024 + blk*16 + c_ep;
    uu = bf2f(u_bf[i0]); zz = bf2f(z_bf[i0]); gg = bf2f(g_bf[i0]); xv = xres[i0];
  }
  __syncthreads();

  // fragment bases: A row = ln&15 (rows>=4 alias zero row), k-chunk = ln>>4
  const int arow = ln & 15, akc = ln >> 4;
  const ushort* Abase = &HL[(arow < 4 ? arow : 4)*1032 + akc*8];
  const ushort* Bbase = &WL[(ln & 15)*1032 + akc*8];
  // consumer mapping: thread t handles words [t*8, t*8+8) = batch t>>6, k [(t&63)*16,+16)
  const int hb_t = t >> 6, hk0 = (t & 63)*16;

  for (int step = 0; step < 4096; ++step) {
    // ---- poll tagged h words through the coherence point ----
    {
      const unsigned long long* hs = h_buf + (size_t)(step & 1)*2048 + t*8;
      u32x4 r0, r1, r2, r3;
      while (true) {
        load8_u64_coherent(hs, r0, r1, r2, r3);
        uint st = (uint)step;
        if (r0.y==st && r0.w==st && r1.y==st && r1.w==st &&
            r2.y==st && r2.w==st && r3.y==st && r3.w==st) break;
      }
      uint* dst = (uint*)&HL[hb_t*1032 + hk0];
      *(uint4*)(dst + 0) = make_uint4(r0.x, r0.z, r1.x, r1.z);
      *(uint4*)(dst + 4) = make_uint4(r2.x, r2.z, r3.x, r3.z);
    }
    __syncthreads();
    // ---- MFMA partial: wave wv covers K in [wv*256, wv*256+256) ----
    f32x4 acc = {0.f,0.f,0.f,0.f};
    #pragma unroll
    for (int m = 0; m < 8; ++m) {
      int koff = wv*256 + m*32;
      s16x8 a = *(const s16x8*)(Abase + koff);
      s16x8 b = *(const s16x8*)(Bbase + koff);
      acc = mfma16(a, b, acc);
    }
    if (ln < 16) *(f32x4*)&red[wv][ln][0] = acc;   // lane=col, regs=rows 0..3
    __syncthreads();
    // ---- epilogue (wave 0) ----
    if (t < 64) {
      float y = red[0][c_ep][b_ep] + red[1][c_ep][b_ep]
              + red[2][c_ep][b_ep] + red[3][c_ep][b_ep];
      float gate = fsigmoid(y + uu);
      float hn = hmine + gate*(zz - hmine) + gg*hmine;
      hmine = hn;
      int colg = blk*16 + c_ep;
      float hup = __shfl_down(hn, 1);
      if ((t & 1) == 0) {     // pack (even,odd) cols + tag, single coherent 64-bit store
        unsigned long long pk = ((unsigned long long)(uint)(step+1) << 32)
                              | ((uint)f2bf(hup) << 16) | (uint)f2bf(hn);
        store_u64_coherent(h_buf + (size_t)((step+1)&1)*2048 + b_ep*512 + (colg>>1), pk);
      }
      size_t idx = ((size_t)(b_ep*4096 + step))*1024 + colg;
      xres[idx] = xv + hn;
      int sn = (step+1 < 4096) ? step+1 : 4095;
      size_t idxn = ((size_t)(b_ep*4096 + sn))*1024 + colg;
      uu = bf2f(u_bf[idxn]); zz = bf2f(z_bf[idxn]); gg = bf2f(g_bf[idxn]);
      xv = xres[idxn];
    }
  }
}

// =======================================================================================
extern "C" void kernel_launch(void* const* d_in, const int* in_sizes, int n_in,
                              void* d_out, int out_size, void* d_ws, size_t ws_size,
                              hipStream_t stream)
{
  const float* x    = (const float*)d_in[0];
  const float* memk = (const float*)d_in[1];
  const float* memv = (const float*)d_in[2];
  const float* n1s  = (const float*)d_in[3];
  const float* n2s  = (const float*)d_in[4];
  const float* Wq = (const float*)d_in[5];   const float* bq = (const float*)d_in[6];
  const float* Wk = (const float*)d_in[7];   const float* bk = (const float*)d_in[8];
  const float* Wv = (const float*)d_in[9];   const float* bv = (const float*)d_in[10];
  const float* Wz = (const float*)d_in[11];  const float* bz = (const float*)d_in[12];
  const float* Wgz = (const float*)d_in[13]; const float* bgz = (const float*)d_in[14];
  const float* Wgh = (const float*)d_in[15]; const float* bgh = (const float*)d_in[16];
  const float* Wg1 = (const float*)d_in[17]; const float* bg1 = (const float*)d_in[18];
  const float* Wg2 = (const float*)d_in[19]; const float* bg2 = (const float*)d_in[20];
  const float* Wgc1 = (const float*)d_in[21]; const float* bgc1 = (const float*)d_in[22];
  const float* Wgc2 = (const float*)d_in[23]; const float* bgc2 = (const float*)d_in[24];
  const float* Awq = (const float*)d_in[25]; const float* abq = (const float*)d_in[26];
  const float* Awk = (const float*)d_in[27]; const float* abk = (const float*)d_in[28];
  const float* Awv = (const float*)d_in[29]; const float* abv = (const float*)d_in[30];
  const float* Awo = (const float*)d_in[31]; const float* abo = (const float*)d_in[32];
  const float* Wf1 = (const float*)d_in[33]; const float* bf1 = (const float*)d_in[34];
  const float* Wf2 = (const float*)d_in[35]; const float* bf2 = (const float*)d_in[36];
  (void)in_sizes; (void)n_in; (void)out_size; (void)ws_size;

  char* ws = (char*)d_ws;
  constexpr size_t MB = 1ull<<20;
  // persistent bf16 weights [0,32MB)
  ushort* WvT     = (ushort*)(ws + 0*MB);
  ushort* WzT     = (ushort*)(ws + 2*MB);
  ushort* WgzT    = (ushort*)(ws + 4*MB);
  ushort* WqAwqT  = (ushort*)(ws + 6*MB);
  ushort* AwkT    = (ushort*)(ws + 8*MB);
  ushort* AwvT    = (ushort*)(ws + 10*MB);
  ushort* AwoT    = (ushort*)(ws + 12*MB);
  ushort* Wf1T    = (ushort*)(ws + 14*MB);            // [4096][1024]
  ushort* Wf2Tc   = (ushort*)(ws + 22*MB);            // 4 chunks of [1024][1024]
  ushort* Wg1T    = (ushort*)(ws + 30*MB);
  ushort* Wg2T    = (ushort*)(ws + 30*MB + 512*1024);
  ushort* Wgc2T   = (ushort*)(ws + 31*MB);
  ushort* WkWgc1T = (ushort*)(ws + 31*MB + 512*1024);
  // small [32MB,33MB)
  float* bsum = (float*)(ws + 32*MB);
  float* bqh  = (float*)(ws + 32*MB + 4096);
  float* bkg  = (float*)(ws + 32*MB + 8192);
  char*  scanB = ws + 32*MB + 65536;                  // tagged h_buf: 2 x 2048 x 8B = 32KB
  // 32MB activation slots
  ushort* Abuf = (ushort*)(ws + 33*MB);   // xn -> gamma
  ushort* Bbuf = (ushort*)(ws + 65*MB);   // z
  ushort* Cbuf = (ushort*)(ws + 97*MB);   // v -> xn2
  ushort* Dbuf = (ushort*)(ws + 129*MB);  // qh -> att -> f1 chunk
  ushort* Ebuf = (ushort*)(ws + 161*MB);  // u
  // scratch inside d_out (64MB), all dead before the Awo epilogue writes d_out
  char* db = (char*)d_out;
  ushort* t1B   = (ushort*)(db + 0);        // 8MB
  ushort* memkB = (ushort*)(db + 8*MB);
  ushort* memvB = (ushort*)(db + 12*MB);
  ushort* khB   = (ushort*)(db + 16*MB);
  ushort* vhTB  = (ushort*)(db + 20*MB);
  ushort* gbB   = (ushort*)(db + 24*MB);    // 32MB
  ushort* WtmpB = (ushort*)(db + 56*MB);    // 2MB fusion A
  ushort* BtTB  = (ushort*)(db + 58*MB);    // 2MB fusion Bt

  const int M1 = 16384;
  dim3 b256(256);
  auto T = [&](const float* s, ushort* d, int K, int N){
    transpose_cvt<<<dim3(N/64, K/64), b256, 0, stream>>>(s, d, K, N);
  };
  #define G(EPI, Ap, Bp, bi, Cp, a0, a1, Mv, Nv, Kv) \
    gemm_bf16<EPI><<<dim3((Nv)/128,(Mv)/128), b256, 0, stream>>>( \
      (const ushort*)(Ap), (const ushort*)(Bp), bi, (void*)(Cp), a0, a1, Mv, Nv, Kv)

  // ---- fused weights (temps in d_out scratch) ----
  cvt_bf16<<<1024, b256, 0, stream>>>(Wq, WtmpB, 1048576);
  T(Awq, BtTB, 1024, 1024);
  G(7, WtmpB, BtTB, nullptr, WqAwqT, nullptr, nullptr, 1024, 1024, 1024);
  fuse_bias<<<4, b256, 0, stream>>>(bq, Awq, abq, bqh, 1024, 1024);
  cvt_bf16<<<1024, b256, 0, stream>>>(Wk, WtmpB, 1048576);
  T(Wgc1, BtTB, 1024, 256);
  G(7, WtmpB, BtTB, nullptr, WkWgc1T, nullptr, nullptr, 1024, 256, 1024);
  fuse_bias<<<1, b256, 0, stream>>>(bk, Wgc1, bgc1, bkg, 1024, 256);
  // ---- plain transposed weights ----
  T(Wv,WvT,1024,1024); T(Wz,WzT,1024,1024); T(Wgz,WgzT,1024,1024);
  T(Wg1,Wg1T,1024,256); T(Wg2,Wg2T,256,1024); T(Wgc2,Wgc2T,256,1024);
  T(Awk,AwkT,1024,1024); T(Awv,AwvT,1024,1024); T(Awo,AwoT,1024,1024);
  T(Wf1,Wf1T,1024,4096);
  for (int cch = 0; cch < 4; ++cch)
    T(Wf2 + (size_t)cch*1048576, Wf2Tc + (size_t)cch*1048576, 1024, 1024);
  bias_sum_k<<<4, b256, 0, stream>>>(bgz, bgh, bsum);
  cvt_bf16<<<2048, b256, 0, stream>>>(memk, memkB, 2097152);
  cvt_bf16<<<2048, b256, 0, stream>>>(memv, memvB, 2097152);

  // ---- forward ----
  rms_kernel<<<M1, b256, 0, stream>>>(x, n1s, Abuf);                    // xn
  G(0, Abuf, WzT, bz, Bbuf, nullptr, nullptr, M1, 1024, 1024);          // z
  G(0, Abuf, WvT, bv, Cbuf, nullptr, nullptr, M1, 1024, 1024);          // v
  G(0, Abuf, WqAwqT, bqh, Dbuf, nullptr, nullptr, M1, 1024, 1024);      // qh (fused)
  G(0, Bbuf, WgzT, bsum, Ebuf, nullptr, nullptr, M1, 1024, 1024);       // u
  G(1, Bbuf, Wg1T, bg1, t1B, nullptr, nullptr, M1, 256, 1024);          // t1z
  G(2, t1B, Wg2T, bg2, gbB, nullptr, nullptr, M1, 1024, 256);           // gamma_base
  G(1, Abuf, WkWgc1T, bkg, t1B, nullptr, nullptr, M1, 256, 1024);       // t1k (fused)
  G(3, t1B, Wgc2T, bgc2, Abuf, gbB, nullptr, M1, 1024, 256);            // gamma -> A
  G(0, memkB, AwkT, abk, khB, nullptr, nullptr, 2048, 1024, 1024);      // kh
  G(6, memvB, AwvT, abv, vhTB, nullptr, nullptr, 2048, 1024, 1024);     // vhT
  attn_kernel<<<dim3(64,8,4), b256, 0, stream>>>(Dbuf, khB, vhTB, Dbuf); // att in-place
  G(4, Dbuf, AwoT, abo, d_out, (const void*)x, (const void*)Cbuf, M1, 1024, 1024); // x+mem+0.1v
  hipMemsetAsync(scanB, 0, 32768, stream);
  scan_kernel<<<SCAN_NB, b256, 0, stream>>>(Wgh, Ebuf, Bbuf, Abuf, (float*)d_out,
                                            (unsigned long long*)scanB);
  rms_kernel<<<M1, b256, 0, stream>>>((const float*)d_out, n2s, Cbuf);  // xn2
  for (int cch = 0; cch < 4; ++cch) {
    G(1, Cbuf, Wf1T + (size_t)cch*1048576, bf1 + cch*1024, Dbuf, nullptr, nullptr, M1, 1024, 1024);
    G(5, Dbuf, Wf2Tc + (size_t)cch*1048576, (cch==0 ? bf2 : nullptr), d_out, nullptr, nullptr, M1, 1024, 1024);
  }
  #undef G
}